// Round 4
// baseline (300.943 us; speedup 1.0000x reference)
//
#include <hip/hip_runtime.h>

#define NN 50000
#define NE 600000
#define D  128
#define NBLK 196
#define BCAP 64                   // bucket slots/node; P(deg>64) ~ 1e-25 for Poisson(12)
#define NTI 12500                 // node tiles per colblock (NN/4)
#define SLICE_U ((NN + 1) * 32)   // ushorts per 32-col slice (3.2 MB: fits per-XCD L2)

typedef __attribute__((ext_vector_type(8))) short bf16x8;
typedef __attribute__((ext_vector_type(4))) float floatx4;
typedef __attribute__((ext_vector_type(2))) float f32x2;
typedef __attribute__((ext_vector_type(2))) unsigned int u32x2;

__device__ __forceinline__ unsigned short bf16_rne(float f) {
    union { float f; unsigned u; } v; v.f = f;
    unsigned r = v.u + 0x7FFFu + ((v.u >> 16) & 1u);
    return (unsigned short)(r >> 16);
}
__device__ __forceinline__ unsigned pack2(float a, float b) {
    return (unsigned)bf16_rne(a) | ((unsigned)bf16_rne(b) << 16);
}

// ---------- prep: deg=0, dummy rows (slice NN) = 0, Wb = bf16(0.5*diag0*W) ----------
__global__ __launch_bounds__(256) void prep_kernel(const float* __restrict__ W,
                                                   const float* __restrict__ diag,
                                                   unsigned short* __restrict__ Wb,
                                                   int* __restrict__ deg_i,
                                                   unsigned int* __restrict__ z0,
                                                   unsigned int* __restrict__ z1) {
    int g = blockIdx.x * 256 + threadIdx.x;
    if (g < NN) deg_i[g] = 0;
    if (g < 16384) Wb[g] = bf16_rne(0.5f * diag[g & 127] * W[g]);
    if (g < 64) {                      // 4 slices x 16 dwords (64B dummy row each)
        int cb = g >> 4, w = g & 15;
        int idx = cb * ((NN + 1) * 16) + NN * 16 + w;
        z0[idx] = 0u; z1[idx] = 0u;
    }
}

// -------- bucket fill: ONE pass builds adjacency; ushort slots (ids < 65536) ------
__global__ __launch_bounds__(256) void bucket_fill_kernel(const int* __restrict__ src,
                                                          const int* __restrict__ dst,
                                                          int* __restrict__ deg_i,
                                                          unsigned short* __restrict__ buck) {
    const int e = (blockIdx.x * 256 + threadIdx.x) * 4;
    if (e >= NE) return;                       // NE % 4 == 0
    const int4 d4 = *(const int4*)(dst + e);
    const int4 s4 = *(const int4*)(src + e);
    int c;
    c = atomicAdd(&deg_i[d4.x], 1); if (c < BCAP) buck[(d4.x << 6) + c] = (unsigned short)s4.x;
    c = atomicAdd(&deg_i[d4.y], 1); if (c < BCAP) buck[(d4.y << 6) + c] = (unsigned short)s4.y;
    c = atomicAdd(&deg_i[d4.z], 1); if (c < BCAP) buck[(d4.z << 6) + c] = (unsigned short)s4.z;
    c = atomicAdd(&deg_i[d4.w], 1); if (c < BCAP) buck[(d4.w << 6) + c] = (unsigned short)s4.w;
}

// ------------------------------- MFMA GEMM (h0) + column-sliced featb byproduct
__global__ __launch_bounds__(256) void gemm_mfma_kernel(const float* __restrict__ feat,
                                                        const unsigned short* __restrict__ Wb,
                                                        const float* __restrict__ b,
                                                        const int* __restrict__ deg_i,
                                                        unsigned short* __restrict__ featbCB,
                                                        float* __restrict__ out) {
    const int wv   = threadIdx.x >> 6;
    const int lane = threadIdx.x & 63;
    const int r16  = lane & 15;
    const int quad = lane >> 4;
    const int m0   = blockIdx.x * 64 + wv * 16;

    const int mrow = m0 + r16;
    const int mc   = (mrow < NN) ? mrow : (NN - 1);
    const float* arow = feat + (size_t)mc * D + quad * 8;
    const float di = rsqrtf(fmaxf((float)deg_i[mc], 1.0f));

    bf16x8 afrag[4];
    #pragma unroll
    for (int kc = 0; kc < 4; ++kc) {
        const floatx4 f0 = __builtin_nontemporal_load((const floatx4*)(arow + kc * 32));
        const floatx4 f1 = __builtin_nontemporal_load((const floatx4*)(arow + kc * 32 + 4));
        bf16x8 a;
        a[0] = (short)bf16_rne(f0[0]); a[1] = (short)bf16_rne(f0[1]);
        a[2] = (short)bf16_rne(f0[2]); a[3] = (short)bf16_rne(f0[3]);
        a[4] = (short)bf16_rne(f1[0]); a[5] = (short)bf16_rne(f1[1]);
        a[6] = (short)bf16_rne(f1[2]); a[7] = (short)bf16_rne(f1[3]);
        afrag[kc] = a;
        if (mrow < NN) {
            uint4 st;
            st.x = pack2(f0[0] * di, f0[1] * di);
            st.y = pack2(f0[2] * di, f0[3] * di);
            st.z = pack2(f1[0] * di, f1[1] * di);
            st.w = pack2(f1[2] * di, f1[3] * di);
            // slice cb = kc; cols quad*8..+7 of slice
            *(uint4*)(featbCB + (size_t)kc * SLICE_U + (size_t)mc * 32 + quad * 8) = st;
        }
    }

    floatx4 acc[8];
    #pragma unroll
    for (int nt = 0; nt < 8; ++nt) acc[nt] = (floatx4)(0.0f);

    #pragma unroll
    for (int nt = 0; nt < 8; ++nt) {
        const unsigned short* brow = Wb + (size_t)(nt * 16 + r16) * D + quad * 8;
        #pragma unroll
        for (int kc = 0; kc < 4; ++kc) {
            const bf16x8 bfrag = *(const bf16x8*)(brow + kc * 32);
            acc[nt] = __builtin_amdgcn_mfma_f32_16x16x32_bf16(afrag[kc], bfrag, acc[nt], 0, 0, 0);
        }
    }

    // C/D layout: col=lane&15 (d), row=quad*4+reg (i)
    #pragma unroll
    for (int nt = 0; nt < 8; ++nt) {
        const int d = nt * 16 + r16;
        const float bd = b[d];
        #pragma unroll
        for (int r = 0; r < 4; ++r) {
            const int i = m0 + quad * 4 + r;
            if (i < NN) __builtin_nontemporal_store(acc[nt][r] + bd, out + (size_t)i * D + d);
        }
    }
}

// --------------------------------------------- column-sliced gather
// Wave handles (node, colblock): lane l covers row-slot (l>>3), cols (l&7)*4..+3.
// One uint2 load per lane per 8 rows (64 lanes = 8 rows x 64 B). Slot-group
// partials reduced via shfl_xor(8,16,32). Rows array = 3.2 MB slice (L2-resident).
__device__ __forceinline__ floatx4 gather_cb(const unsigned short* __restrict__ rows,
                                             const unsigned short* __restrict__ buck,
                                             int node, int bcnt, int lane) {
    const int slot = lane >> 3;
    const unsigned lane_b = (unsigned)((lane & 7) << 3);    // byte offset in 64B row-slice
    int s = (lane < bcnt) ? (int)__builtin_nontemporal_load(&buck[(node << 6) + lane]) : NN;
    f32x2 a01 = (f32x2)(0.0f);
    f32x2 a23 = (f32x2)(0.0f);
    const int cnt8 = (bcnt + 7) & ~7;
    for (int k = 0; k < cnt8; k += 8) {
        int ss = __shfl(s, k + slot);
        const u32x2 pv = *(const u32x2*)((const char*)rows + (((unsigned)ss << 6) | lane_b));
        f32x2 lo0, lo1;
        lo0.x = __uint_as_float(pv.x << 16);
        lo0.y = __uint_as_float(pv.x & 0xFFFF0000u);
        lo1.x = __uint_as_float(pv.y << 16);
        lo1.y = __uint_as_float(pv.y & 0xFFFF0000u);
        a01 += lo0;
        a23 += lo1;
    }
    floatx4 r; r[0] = a01.x; r[1] = a01.y; r[2] = a23.x; r[3] = a23.y;
    #pragma unroll
    for (int m = 8; m <= 32; m <<= 1) {
        r[0] += __shfl_xor(r[0], m);
        r[1] += __shfl_xor(r[1], m);
        r[2] += __shfl_xor(r[2], m);
        r[3] += __shfl_xor(r[3], m);
    }
    return r;
}

// round 1: feat1CB[cb] = bf16( (feat0 - acc*dinv_i*diag1) * dinv_i ), 32 cols/wave
__global__ __launch_bounds__(256) void gather1_kernel(const unsigned short* __restrict__ featbCB,
                                                      const unsigned short* __restrict__ buck,
                                                      const int* __restrict__ deg_i,
                                                      const float* __restrict__ diag,
                                                      const float* __restrict__ feat0,
                                                      unsigned short* __restrict__ feat1CB) {
    const int cb   = blockIdx.x / NTI;          // colblock-major: L2 slice stays hot
    const int node = (blockIdx.x - cb * NTI) * 4 + (threadIdx.x >> 6);
    const int lane = threadIdx.x & 63;
    const int dg   = deg_i[node];
    const unsigned short* rows = featbCB + (size_t)cb * SLICE_U;
    floatx4 acc = gather_cb(rows, buck, node, min(dg, BCAP), lane);
    if (lane < 8) {
        const int c0 = cb * 32 + lane * 4;
        const float di = rsqrtf(fmaxf((float)dg, 1.0f));
        const floatx4 bs = __builtin_nontemporal_load((const floatx4*)(feat0 + (size_t)node * D + c0));
        const floatx4 dgv = *(const floatx4*)(diag + D + c0);
        const float r0 = (bs[0] - acc[0] * di * dgv[0]) * di;
        const float r1 = (bs[1] - acc[1] * di * dgv[1]) * di;
        const float r2 = (bs[2] - acc[2] * di * dgv[2]) * di;
        const float r3 = (bs[3] - acc[3] * di * dgv[3]) * di;
        u32x2 st; st.x = pack2(r0, r1); st.y = pack2(r2, r3);
        *(u32x2*)(feat1CB + (size_t)cb * SLICE_U + (size_t)node * 32 + lane * 4) = st;
    }
}

// round 2: out += -0.5*(feat1 + acc*dinv_i*diag2), feat1 = feat1CB*rdeg_i
__global__ __launch_bounds__(256) void gather2_kernel(const unsigned short* __restrict__ feat1CB,
                                                      const unsigned short* __restrict__ buck,
                                                      const int* __restrict__ deg_i,
                                                      const float* __restrict__ diag,
                                                      float* __restrict__ outp) {
    const int cb   = blockIdx.x / NTI;
    const int node = (blockIdx.x - cb * NTI) * 4 + (threadIdx.x >> 6);
    const int lane = threadIdx.x & 63;
    const int dg   = deg_i[node];
    const unsigned short* rows = feat1CB + (size_t)cb * SLICE_U;
    floatx4 acc = gather_cb(rows, buck, node, min(dg, BCAP), lane);
    if (lane < 8) {
        const int c0 = cb * 32 + lane * 4;
        const float dc = fmaxf((float)dg, 1.0f);
        const float di = rsqrtf(dc);
        const float rd = sqrtf(dc);
        const u32x2 bp = *(const u32x2*)(feat1CB + (size_t)cb * SLICE_U + (size_t)node * 32 + lane * 4);
        const float b0 = __uint_as_float(bp.x << 16) * rd;          // unscale
        const float b1 = __uint_as_float(bp.x & 0xFFFF0000u) * rd;
        const float b2 = __uint_as_float(bp.y << 16) * rd;
        const float b3 = __uint_as_float(bp.y & 0xFFFF0000u) * rd;
        const floatx4 dgv = *(const floatx4*)(diag + 2 * D + c0);
        float* op = outp + (size_t)node * D + c0;
        floatx4 cur = __builtin_nontemporal_load((const floatx4*)op);
        cur[0] -= 0.5f * (b0 + acc[0] * di * dgv[0]);
        cur[1] -= 0.5f * (b1 + acc[1] * di * dgv[1]);
        cur[2] -= 0.5f * (b2 + acc[2] * di * dgv[2]);
        cur[3] -= 0.5f * (b3 + acc[3] * di * dgv[3]);
        __builtin_nontemporal_store(cur, (floatx4*)op);
    }
}

// ----------------------------------------------------------------- launch
extern "C" void kernel_launch(void* const* d_in, const int* in_sizes, int n_in,
                              void* d_out, int out_size, void* d_ws, size_t ws_size,
                              hipStream_t stream) {
    const float* feat = (const float*)d_in[0];
    const int*   eidx = (const int*)d_in[1];
    const float* diag = (const float*)d_in[2];
    const float* W    = (const float*)d_in[3];
    const float* b    = (const float*)d_in[4];
    float* out = (float*)d_out;

    const int* src = eidx;            // edge_index[0]
    const int* dst = eidx + NE;       // edge_index[1]

    // ---- workspace layout (~32.2 MB) ----
    unsigned short* featbCB = (unsigned short*)d_ws;               // 4 * SLICE_U ush
    unsigned short* feat1CB = featbCB + 4 * (size_t)SLICE_U;       // 4 * SLICE_U ush
    unsigned short* buck16  = feat1CB + 4 * (size_t)SLICE_U;       // NN*64 ush
    int*   deg_i   = (int*)(buck16 + (size_t)NN * BCAP);           // NN
    unsigned short* Wb = (unsigned short*)(deg_i + NN);            // 32 KB

    // prep: deg=0, dummy rows=0, Wb
    prep_kernel<<<NBLK, 256, 0, stream>>>(W, diag, Wb, deg_i,
                                          (unsigned int*)featbCB, (unsigned int*)feat1CB);

    // single-pass bucketed adjacency build
    bucket_fill_kernel<<<(NE / 4 + 255) / 256, 256, 0, stream>>>(src, dst, deg_i, buck16);

    // out = h0 + b; featbCB = bf16(feat*dinv) byproduct (column-sliced)
    gemm_mfma_kernel<<<(NN + 63) / 64, 256, 0, stream>>>(feat, Wb, b, deg_i, featbCB, out);

    // round 1: feat1CB = bf16(feat1 * dinv)  (colblock-major grid)
    gather1_kernel<<<4 * NTI, 256, 0, stream>>>(featbCB, buck16, deg_i, diag, feat, feat1CB);
    // round 2: out += -0.5*(feat1 + agg2*dinv*diag2)
    gather2_kernel<<<4 * NTI, 256, 0, stream>>>(feat1CB, buck16, deg_i, diag, out);
}

// Round 5
// 196.021 us; speedup vs baseline: 1.5353x; 1.5353x over previous
//
#include <hip/hip_runtime.h>

#define NN 50000
#define NE 600000
#define D  128
#define NBLK 196      // ceil(NN/256)
#define BCAP 64       // bucket slots per node; P(deg>64) ~ 1e-25 for Poisson(12)

typedef __attribute__((ext_vector_type(8))) short bf16x8;
typedef __attribute__((ext_vector_type(4))) float floatx4;
typedef __attribute__((ext_vector_type(2))) float f32x2;
typedef __attribute__((ext_vector_type(2))) unsigned int u32x2;

__device__ __forceinline__ unsigned short bf16_rne(float f) {
    union { float f; unsigned u; } v; v.f = f;
    unsigned r = v.u + 0x7FFFu + ((v.u >> 16) & 1u);
    return (unsigned short)(r >> 16);
}
__device__ __forceinline__ unsigned pack2(float a, float b) {
    return (unsigned)bf16_rne(a) | ((unsigned)bf16_rne(b) << 16);
}

// ---------- prep: deg=0, dummy rows=0, Wb = bf16(0.5*diag0*W) ----------
__global__ __launch_bounds__(256) void prep_kernel(const float* __restrict__ W,
                                                   const float* __restrict__ diag,
                                                   unsigned short* __restrict__ Wb,
                                                   int* __restrict__ deg_i,
                                                   unsigned int* __restrict__ zrow0,
                                                   unsigned int* __restrict__ zrow1) {
    int g = blockIdx.x * 256 + threadIdx.x;
    if (g < NN) deg_i[g] = 0;
    if (g < 16384) {
        int j = g & 127;
        Wb[g] = bf16_rne(0.5f * diag[j] * W[g]);
    }
    if (g < 64) { zrow0[g] = 0u; zrow1[g] = 0u; }
}

// -------- bucket fill: ONE pass builds adjacency (no hist/scan/fill chain) ------
// buck[dst*64 + c] = src, c = running count. 4 edges/thread, int4 loads.
__global__ __launch_bounds__(256) void bucket_fill_kernel(const int* __restrict__ src,
                                                          const int* __restrict__ dst,
                                                          int* __restrict__ deg_i,
                                                          int* __restrict__ buck) {
    const int e = (blockIdx.x * 256 + threadIdx.x) * 4;
    if (e >= NE) return;                       // NE % 4 == 0: full groups only
    const int4 d4 = *(const int4*)(dst + e);
    const int4 s4 = *(const int4*)(src + e);
    int c;
    c = atomicAdd(&deg_i[d4.x], 1); if (c < BCAP) buck[(d4.x << 6) + c] = s4.x;
    c = atomicAdd(&deg_i[d4.y], 1); if (c < BCAP) buck[(d4.y << 6) + c] = s4.y;
    c = atomicAdd(&deg_i[d4.z], 1); if (c < BCAP) buck[(d4.z << 6) + c] = s4.z;
    c = atomicAdd(&deg_i[d4.w], 1); if (c < BCAP) buck[(d4.w << 6) + c] = s4.w;
}

// ------------------------------- MFMA GEMM (h0) + featb_s byproduct
// dinv computed on the fly from deg_i (rsqrtf(max(deg,1)) — same values as before).
__global__ __launch_bounds__(256) void gemm_mfma_kernel(const float* __restrict__ feat,
                                                        const unsigned short* __restrict__ Wb,
                                                        const float* __restrict__ b,
                                                        const int* __restrict__ deg_i,
                                                        unsigned short* __restrict__ featb_s,
                                                        float* __restrict__ out) {
    const int wv   = threadIdx.x >> 6;
    const int lane = threadIdx.x & 63;
    const int r16  = lane & 15;
    const int quad = lane >> 4;
    const int m0   = blockIdx.x * 64 + wv * 16;

    const int mrow = m0 + r16;
    const int mc   = (mrow < NN) ? mrow : (NN - 1);
    const float* arow = feat + (size_t)mc * D + quad * 8;
    const float di = rsqrtf(fmaxf((float)deg_i[mc], 1.0f));

    bf16x8 afrag[4];
    #pragma unroll
    for (int kc = 0; kc < 4; ++kc) {
        const float4 f0 = *(const float4*)(arow + kc * 32);
        const float4 f1 = *(const float4*)(arow + kc * 32 + 4);
        bf16x8 a;
        a[0] = (short)bf16_rne(f0.x); a[1] = (short)bf16_rne(f0.y);
        a[2] = (short)bf16_rne(f0.z); a[3] = (short)bf16_rne(f0.w);
        a[4] = (short)bf16_rne(f1.x); a[5] = (short)bf16_rne(f1.y);
        a[6] = (short)bf16_rne(f1.z); a[7] = (short)bf16_rne(f1.w);
        afrag[kc] = a;
        if (mrow < NN) {
            uint4 st;
            st.x = pack2(f0.x * di, f0.y * di);
            st.y = pack2(f0.z * di, f0.w * di);
            st.z = pack2(f1.x * di, f1.y * di);
            st.w = pack2(f1.z * di, f1.w * di);
            *(uint4*)(featb_s + (size_t)mc * D + quad * 8 + kc * 32) = st;
        }
    }

    floatx4 acc[8];
    #pragma unroll
    for (int nt = 0; nt < 8; ++nt) acc[nt] = (floatx4)(0.0f);

    #pragma unroll
    for (int nt = 0; nt < 8; ++nt) {
        const unsigned short* brow = Wb + (size_t)(nt * 16 + r16) * D + quad * 8;
        #pragma unroll
        for (int kc = 0; kc < 4; ++kc) {
            const bf16x8 bfrag = *(const bf16x8*)(brow + kc * 32);
            acc[nt] = __builtin_amdgcn_mfma_f32_16x16x32_bf16(afrag[kc], bfrag, acc[nt], 0, 0, 0);
        }
    }

    // C/D layout: col=lane&15 (d), row=quad*4+reg (i)
    #pragma unroll
    for (int nt = 0; nt < 8; ++nt) {
        const int d = nt * 16 + r16;
        const float bd = b[d];
        #pragma unroll
        for (int r = 0; r < 4; ++r) {
            const int i = m0 + quad * 4 + r;
            if (i < NN) out[(size_t)i * D + d] = acc[nt][r] + bd;
        }
    }
}

// --------------------------------------------- shared gather inner loop
// Bucketed: node's neighbors at buck[node*64 .. node*64+bcnt), bcnt<=64.
// 2 rows per load-step via lane halves (lanes 0-31 even slots, 32-63 odd).
// MLP: 16-row chunks -> 8 independent uint2 loads batched before accumulation.
// Accumulation sequence identical to prior rounds (bit-identical result).
__device__ __forceinline__ floatx4 gather_acc(const unsigned short* __restrict__ rows,
                                              const int* __restrict__ buck,
                                              int node, int bcnt, int lane) {
    const int half = lane >> 5;
    const unsigned lane_b = (unsigned)((lane & 31) << 3);   // byte offset in 256B row
    int s = (lane < bcnt) ? buck[(node << 6) + lane] : NN;  // NN = zero dummy row
    f32x2 a01 = (f32x2)(0.0f);
    f32x2 a23 = (f32x2)(0.0f);
    const int cnt16 = (bcnt + 15) & ~15;
    for (int k = 0; k < cnt16; k += 16) {
        u32x2 pv[8];
        #pragma unroll
        for (int u = 0; u < 8; ++u) {            // 8 independent loads in flight
            int ss = __shfl(s, k + 2 * u + half);
            pv[u] = *(const u32x2*)((const char*)rows + (((unsigned)ss << 8) | lane_b));
        }
        #pragma unroll
        for (int u = 0; u < 8; ++u) {
            f32x2 lo0, lo1;
            lo0.x = __uint_as_float(pv[u].x << 16);
            lo0.y = __uint_as_float(pv[u].x & 0xFFFF0000u);
            lo1.x = __uint_as_float(pv[u].y << 16);
            lo1.y = __uint_as_float(pv[u].y & 0xFFFF0000u);
            a01 += lo0;
            a23 += lo1;
        }
    }
    floatx4 r;
    r[0] = a01.x; r[1] = a01.y; r[2] = a23.x; r[3] = a23.y;
    #pragma unroll
    for (int i = 0; i < 4; ++i) r[i] += __shfl_xor(r[i], 32);
    return r;
}

// round 1: feat1s = bf16( (feat0 - acc*dinv_i*diag1) * dinv_i )
__global__ __launch_bounds__(256) void gather1_kernel(const unsigned short* __restrict__ featb_s,
                                                      const int* __restrict__ buck,
                                                      const int* __restrict__ deg_i,
                                                      const float* __restrict__ diag,
                                                      const float* __restrict__ feat0,
                                                      unsigned short* __restrict__ feat1s) {
    const int node = blockIdx.x * 4 + (threadIdx.x >> 6);
    const int lane = threadIdx.x & 63;
    const int dg   = deg_i[node];
    floatx4 acc = gather_acc(featb_s, buck, node, min(dg, BCAP), lane);
    if (lane < 32) {
        const int c0 = lane << 2;
        const float di = rsqrtf(fmaxf((float)dg, 1.0f));
        const float4 bs = *(const float4*)(feat0 + (size_t)node * D + c0);
        const float4 dg4 = *(const float4*)(diag + D + c0);
        const float r0 = (bs.x - acc[0] * di * dg4.x) * di;
        const float r1 = (bs.y - acc[1] * di * dg4.y) * di;
        const float r2 = (bs.z - acc[2] * di * dg4.z) * di;
        const float r3 = (bs.w - acc[3] * di * dg4.w) * di;
        uint2 st; st.x = pack2(r0, r1); st.y = pack2(r2, r3);
        *(uint2*)((char*)feat1s + ((size_t)node << 8) + (lane << 3)) = st;
    }
}

// round 2: out += -0.5*(feat1 + acc*dinv_i*diag2),  feat1 = feat1s*rdeg_i
__global__ __launch_bounds__(256) void gather2_kernel(const unsigned short* __restrict__ feat1s,
                                                      const int* __restrict__ buck,
                                                      const int* __restrict__ deg_i,
                                                      const float* __restrict__ diag,
                                                      float* __restrict__ outp) {
    const int node = blockIdx.x * 4 + (threadIdx.x >> 6);
    const int lane = threadIdx.x & 63;
    const int dg   = deg_i[node];
    floatx4 acc = gather_acc(feat1s, buck, node, min(dg, BCAP), lane);
    if (lane < 32) {
        const int c0 = lane << 2;
        const float dc = fmaxf((float)dg, 1.0f);
        const float di = rsqrtf(dc);
        const float rd = sqrtf(dc);
        const uint2 bp = *(const uint2*)((const char*)feat1s + ((size_t)node << 8) + (lane << 3));
        const float b0 = __uint_as_float(bp.x << 16) * rd;          // unscale
        const float b1 = __uint_as_float(bp.x & 0xFFFF0000u) * rd;
        const float b2 = __uint_as_float(bp.y << 16) * rd;
        const float b3 = __uint_as_float(bp.y & 0xFFFF0000u) * rd;
        const float4 dg4 = *(const float4*)(diag + 2 * D + c0);
        float4 cur = *(float4*)(outp + (size_t)node * D + c0);
        cur.x -= 0.5f * (b0 + acc[0] * di * dg4.x);
        cur.y -= 0.5f * (b1 + acc[1] * di * dg4.y);
        cur.z -= 0.5f * (b2 + acc[2] * di * dg4.z);
        cur.w -= 0.5f * (b3 + acc[3] * di * dg4.w);
        *(float4*)(outp + (size_t)node * D + c0) = cur;
    }
}

// ----------------------------------------------------------------- launch
extern "C" void kernel_launch(void* const* d_in, const int* in_sizes, int n_in,
                              void* d_out, int out_size, void* d_ws, size_t ws_size,
                              hipStream_t stream) {
    const float* feat = (const float*)d_in[0];
    const int*   eidx = (const int*)d_in[1];
    const float* diag = (const float*)d_in[2];
    const float* W    = (const float*)d_in[3];
    const float* b    = (const float*)d_in[4];
    float* out = (float*)d_out;

    const int* src = eidx;            // edge_index[0]
    const int* dst = eidx + NE;       // edge_index[1]

    // ---- workspace layout (~38.6 MB) ----
    unsigned short* featb_s = (unsigned short*)d_ws;             // (NN+1)*D bf16
    unsigned short* feat1s  = featb_s + (size_t)(NN + 1) * D;    // (NN+1)*D bf16
    int*   buck    = (int*)(feat1s + (size_t)(NN + 1) * D);      // NN*64 ints
    int*   deg_i   = buck + (size_t)NN * BCAP;                   // NN
    unsigned short* Wb = (unsigned short*)(deg_i + NN);          // 32 KB

    unsigned int* zr0 = (unsigned int*)(featb_s + (size_t)NN * D);
    unsigned int* zr1 = (unsigned int*)(feat1s + (size_t)NN * D);

    // prep: deg=0, dummy rows=0, Wb
    prep_kernel<<<NBLK, 256, 0, stream>>>(W, diag, Wb, deg_i, zr0, zr1);

    // single-pass bucketed adjacency build
    bucket_fill_kernel<<<(NE / 4 + 255) / 256, 256, 0, stream>>>(src, dst, deg_i, buck);

    // out = h0 + b; featb_s = bf16(feat*dinv) byproduct
    gemm_mfma_kernel<<<(NN + 63) / 64, 256, 0, stream>>>(feat, Wb, b, deg_i, featb_s, out);

    // round 1: feat1s = bf16(feat1 * dinv)
    gather1_kernel<<<NN / 4, 256, 0, stream>>>(featb_s, buck, deg_i, diag, feat, feat1s);
    // round 2: out += -0.5*(feat1 + agg2*dinv*diag2)
    gather2_kernel<<<NN / 4, 256, 0, stream>>>(feat1s, buck, deg_i, diag, out);
}